// Round 6
// baseline (167.077 us; speedup 1.0000x reference)
//
#include <hip/hip_runtime.h>
#include <math.h>

#define NB   8
#define SEQ  2048
#define EMB  8
#define NH   4
#define NFF  2048
#define NTOK (NB*SEQ)          // 16384
#define LNEPS 1e-5f

__device__ __forceinline__ float dot8(const float4& a, const float4& b,
                                      const float4& c, const float4& d) {
    return a.x*b.x + a.y*b.y + a.z*b.z + a.w*b.w
         + c.x*d.x + c.y*d.y + c.z*d.z + c.w*d.w;
}

// ---------------------------------------------------------------------------
// projH[(b*4+h)][s][2] = (x @ Wp^T) head-major, and W2T[f][e] = W2[e][f]
// ---------------------------------------------------------------------------
__global__ __launch_bounds__(256) void k_prep(const float* __restrict__ x,
                                              const float* __restrict__ Wp,
                                              const float* __restrict__ W2,
                                              float* __restrict__ projH,
                                              float* __restrict__ w2t) {
    int t = blockIdx.x * 256 + threadIdx.x;
    if (t < NTOK) {
        int b = t >> 11, s = t & (SEQ - 1);
        const float4* xr = (const float4*)(x + (size_t)t * EMB);
        float4 xa = xr[0], xb = xr[1];
        float o[8];
#pragma unroll
        for (int e = 0; e < 8; ++e) {
            const float4* wr = (const float4*)(Wp + e * EMB);
            o[e] = dot8(xa, wr[0], xb, wr[1]);
        }
#pragma unroll
        for (int h = 0; h < 4; ++h) {
            *(float2*)(projH + ((size_t)(b * 4 + h) * SEQ + s) * 2) =
                make_float2(o[2 * h], o[2 * h + 1]);
        }
    }
    if (t < NFF) {
        float o[8];
#pragma unroll
        for (int e = 0; e < 8; ++e) o[e] = W2[e * NFF + t];
        float4* wr = (float4*)(w2t + (size_t)t * EMB);
        wr[0] = make_float4(o[0], o[1], o[2], o[3]);
        wr[1] = make_float4(o[4], o[5], o[6], o[7]);
    }
}

// ---------------------------------------------------------------------------
// attention (unchanged from R5 — proven numerics/config).
// Block: 256 thr = 8 key-subranges x 32 queries, grid 2048 (8 blocks/CU).
// K staged in LDS as SoA, pre-scaled by 1/sqrt(2).
// ---------------------------------------------------------------------------
#define QC 32
__global__ __launch_bounds__(256) void k_attn(const float* __restrict__ projH,
                                              float* __restrict__ ctx) {
    __shared__ float Kx[SEQ];               // 8 KB  (pre-scaled by 1/sqrt2)
    __shared__ float Ky[SEQ];               // 8 KB
    __shared__ float red[3][8][QC];         // 3 KB

    int bid = blockIdx.x;
    int qc  = bid & 63;                     // 64 query chunks of 32
    int bh  = bid >> 6;                     // (b*4+h)

    const float SC = 0.70710678118654752f;  // 1/sqrt(DK)
    const float4* gsr = (const float4*)(projH + (size_t)bh * SEQ * 2);
    for (int i = threadIdx.x; i < SEQ / 2; i += 256) {
        float4 v = gsr[i];                  // keys 2i,2i+1: (x0,y0,x1,y1)
        *(float2*)&Kx[2 * i] = make_float2(v.x * SC, v.z * SC);
        *(float2*)&Ky[2 * i] = make_float2(v.y * SC, v.w * SC);
    }
    __syncthreads();

    int ql  = threadIdx.x & 31;
    int sub = threadIdx.x >> 5;             // 8 subranges, uniform per half-wave
    int qi  = qc * QC + ql;

    const float SQ2 = 1.41421356237309505f;
    float qx = Kx[qi] * SQ2, qy = Ky[qi] * SQ2;

    float l0 = 0.f, ax0 = 0.f, ay0 = 0.f;
    float l1 = 0.f, ax1 = 0.f, ay1 = 0.f;

    const float4* Kx4 = (const float4*)Kx;
    const float4* Ky4 = (const float4*)Ky;
    int j04 = sub * (SEQ / 8 / 4);
#pragma unroll 4
    for (int jj = 0; jj < SEQ / 8 / 4; ++jj) {
        float4 kx = Kx4[j04 + jj];
        float4 ky = Ky4[j04 + jj];
        float s0 = fmaf(qy, ky.x, qx * kx.x);
        float s1 = fmaf(qy, ky.y, qx * kx.y);
        float s2 = fmaf(qy, ky.z, qx * kx.z);
        float s3 = fmaf(qy, ky.w, qx * kx.w);
        float p0 = __expf(s0);
        float p1 = __expf(s1);
        float p2 = __expf(s2);
        float p3 = __expf(s3);
        l0 += p0;                l1 += p1;
        ax0 = fmaf(p0, kx.x, ax0); ax1 = fmaf(p1, kx.y, ax1);
        ay0 = fmaf(p0, ky.x, ay0); ay1 = fmaf(p1, ky.y, ay1);
        l0 += p2;                l1 += p3;
        ax0 = fmaf(p2, kx.z, ax0); ax1 = fmaf(p3, kx.w, ax1);
        ay0 = fmaf(p2, ky.z, ay0); ay1 = fmaf(p3, ky.w, ay1);
    }
    red[0][sub][ql] = l0 + l1;
    red[1][sub][ql] = ax0 + ax1;
    red[2][sub][ql] = ay0 + ay1;
    __syncthreads();

    if (threadIdx.x < QC) {
        float L = 0.f, A0 = 0.f, A1 = 0.f;
#pragma unroll
        for (int s = 0; s < 8; ++s) {
            L  += red[0][s][threadIdx.x];
            A0 += red[1][s][threadIdx.x];
            A1 += red[2][s][threadIdx.x];
        }
        float inv = SQ2 / L;                // undo the 1/sqrt2 on staged k
        int b = bh >> 2, h = bh & 3;
        int qg = qc * QC + threadIdx.x;
        *(float2*)(ctx + ((size_t)b * SEQ + qg) * EMB + 2 * h) =
            make_float2(A0 * inv, A1 * inv);
    }
}

// ---------------------------------------------------------------------------
// FUSED post+FFN.  TB=16 tokens/block, grid=1024 (4 blocks/CU).
// Prologue (128 lanes = 16 tok x 8 e): attn_out = ctx@Wo^T, LN1 via 8-lane
// shuffles, outq = prefix-prod(cos) via 8-lane scan -> q_lds/x1_lds.
// Main: thread = (tg: 2 tokens) x (sub: 64-f chunk); W1/w2t rows amortized
// over 2 tokens.  XOR-swizzled LDS reduce, LN2 via 8-lane shuffles.
// ---------------------------------------------------------------------------
#define TB   16                 // tokens per block
#define NSUB 32                 // f subranges
#define FCH  (NFF / NSUB)       // 64 f per thread
__global__ __launch_bounds__(256) void k_ffn2(const float* __restrict__ ctx,
                                              const float* __restrict__ x,
                                              const float* __restrict__ Wo,
                                              const float* __restrict__ g1,
                                              const float* __restrict__ b1,
                                              const float* __restrict__ W1,
                                              const float* __restrict__ bb1,
                                              const float* __restrict__ w2t,
                                              const float* __restrict__ bb2,
                                              const float* __restrict__ g2,
                                              const float* __restrict__ b2,
                                              float* __restrict__ out) {
    __shared__ float red[NSUB][TB][8];      // 16 KB, XOR-swizzled rows
    __shared__ float q_lds[TB][8];
    __shared__ float x1_lds[TB][8];

    int tid = threadIdx.x;

    // ---- prologue: post-attention for this block's 16 tokens ----
    if (tid < TB * 8) {
        int tl = tid >> 3, e = tid & 7;
        int tok = blockIdx.x * TB + tl;
        const float4* cr = (const float4*)(ctx + (size_t)tok * EMB);
        float4 ca = cr[0], cb = cr[1];      // broadcast across the 8 lanes
        const float4* wr = (const float4*)(Wo + e * EMB);
        float ao = dot8(ca, wr[0], cb, wr[1]);
        float y = x[(size_t)tok * EMB + e] + ao;

        float s8 = y;
        s8 += __shfl_xor(s8, 1);
        s8 += __shfl_xor(s8, 2);
        s8 += __shfl_xor(s8, 4);
        float mu = s8 * 0.125f;
        float d  = y - mu;
        float vs = d * d;
        vs += __shfl_xor(vs, 1);
        vs += __shfl_xor(vs, 2);
        vs += __shfl_xor(vs, 4);
        float r = rsqrtf(vs * 0.125f + LNEPS);
        float v = d * r * g1[e] + b1[e];
        x1_lds[tl][e] = v;

        // inclusive prefix product of cos over the 8 lanes of this token
        float p = __cosf(v);
        float t1 = __shfl_up(p, 1, 8); p = (e >= 1) ? p * t1 : p;
        float t2 = __shfl_up(p, 2, 8); p = (e >= 2) ? p * t2 : p;
        float t4 = __shfl_up(p, 4, 8); p = (e >= 4) ? p * t4 : p;
        q_lds[tl][e] = p;
    }
    __syncthreads();

    // ---- main FFN loop: 2 tokens x 64 f per thread ----
    int sub = tid & 31;                     // 32 f-subranges
    int tg  = tid >> 5;                     // 8 groups x 2 tokens
    int tl0 = tg * 2;

    float4 qa0 = *(const float4*)&q_lds[tl0][0];
    float4 qb0 = *(const float4*)&q_lds[tl0][4];
    float4 qa1 = *(const float4*)&q_lds[tl0 + 1][0];
    float4 qb1 = *(const float4*)&q_lds[tl0 + 1][4];

    float acc0[8], acc1[8];
#pragma unroll
    for (int e = 0; e < 8; ++e) { acc0[e] = 0.f; acc1[e] = 0.f; }

    int f0 = sub * FCH;
#pragma unroll 2
    for (int i = 0; i < FCH; ++i) {
        int f = f0 + i;
        const float4* w1r = (const float4*)(W1 + (size_t)f * EMB);
        float4 wa = w1r[0], wb = w1r[1];
        float bias = bb1[f];
        const float4* w2r = (const float4*)(w2t + (size_t)f * EMB);
        float4 va = w2r[0], vb = w2r[1];
        float h0 = fmaxf(dot8(qa0, wa, qb0, wb) + bias, 0.f);
        float h1 = fmaxf(dot8(qa1, wa, qb1, wb) + bias, 0.f);
        acc0[0] = fmaf(h0, va.x, acc0[0]);  acc1[0] = fmaf(h1, va.x, acc1[0]);
        acc0[1] = fmaf(h0, va.y, acc0[1]);  acc1[1] = fmaf(h1, va.y, acc1[1]);
        acc0[2] = fmaf(h0, va.z, acc0[2]);  acc1[2] = fmaf(h1, va.z, acc1[2]);
        acc0[3] = fmaf(h0, va.w, acc0[3]);  acc1[3] = fmaf(h1, va.w, acc1[3]);
        acc0[4] = fmaf(h0, vb.x, acc0[4]);  acc1[4] = fmaf(h1, vb.x, acc1[4]);
        acc0[5] = fmaf(h0, vb.y, acc0[5]);  acc1[5] = fmaf(h1, vb.y, acc1[5]);
        acc0[6] = fmaf(h0, vb.z, acc0[6]);  acc1[6] = fmaf(h1, vb.z, acc1[6]);
        acc0[7] = fmaf(h0, vb.w, acc0[7]);  acc1[7] = fmaf(h1, vb.w, acc1[7]);
    }

    // XOR-swizzled store (row = tok ^ (sub&7)) to spread banks
    {
        int r0 = tl0 ^ (sub & 7);
        int r1 = (tl0 + 1) ^ (sub & 7);
        float4* d0 = (float4*)&red[sub][r0][0];
        d0[0] = make_float4(acc0[0], acc0[1], acc0[2], acc0[3]);
        d0[1] = make_float4(acc0[4], acc0[5], acc0[6], acc0[7]);
        float4* d1 = (float4*)&red[sub][r1][0];
        d1[0] = make_float4(acc1[0], acc1[1], acc1[2], acc1[3]);
        d1[1] = make_float4(acc1[4], acc1[5], acc1[6], acc1[7]);
    }
    __syncthreads();

    // ---- reduce + LN2 (128 lanes = 16 tok x 8 e) ----
    if (tid < TB * 8) {
        int rtok = tid >> 3, re = tid & 7;
        float v = 0.f;
#pragma unroll
        for (int s = 0; s < NSUB; ++s) v += red[s][rtok ^ (s & 7)][re];
        int tok = blockIdx.x * TB + rtok;
        v += bb2[re] + x1_lds[rtok][re];

        float s8 = v;
        s8 += __shfl_xor(s8, 1);
        s8 += __shfl_xor(s8, 2);
        s8 += __shfl_xor(s8, 4);
        float mu = s8 * 0.125f;
        float d  = v - mu;
        float vs = d * d;
        vs += __shfl_xor(vs, 1);
        vs += __shfl_xor(vs, 2);
        vs += __shfl_xor(vs, 4);
        float r = rsqrtf(vs * 0.125f + LNEPS);
        out[(size_t)tok * EMB + re] = d * r * g2[re] + b2[re];
    }
}

// ---------------------------------------------------------------------------
extern "C" void kernel_launch(void* const* d_in, const int* in_sizes, int n_in,
                              void* d_out, int out_size, void* d_ws, size_t ws_size,
                              hipStream_t stream) {
    const float* x   = (const float*)d_in[0];
    const float* Wp  = (const float*)d_in[1];
    const float* Wo  = (const float*)d_in[2];
    const float* g1  = (const float*)d_in[3];
    const float* b1  = (const float*)d_in[4];
    const float* W1  = (const float*)d_in[5];
    const float* bb1 = (const float*)d_in[6];
    const float* W2  = (const float*)d_in[7];
    const float* bb2 = (const float*)d_in[8];
    const float* g2  = (const float*)d_in[9];
    const float* b2  = (const float*)d_in[10];
    float* out = (float*)d_out;

    float* ws    = (float*)d_ws;
    float* projH = ws;                // 131072 f32 (head-major)
    float* ctx   = ws + 131072;       // 131072 f32
    float* w2t   = ws + 262144;       // 16384 f32

    hipLaunchKernelGGL(k_prep, dim3(NTOK / 256), dim3(256), 0, stream,
                       x, Wp, W2, projH, w2t);
    hipLaunchKernelGGL(k_attn, dim3(NB * NH * (SEQ / QC)), dim3(256), 0, stream,
                       projH, ctx);
    hipLaunchKernelGGL(k_ffn2, dim3(NTOK / TB), dim3(256), 0, stream,
                       ctx, x, Wo, g1, b1, W1, bb1, w2t, bb2, g2, b2, out);
}

// Round 7
// 62.203 us; speedup vs baseline: 2.6860x; 2.6860x over previous
//
#include <hip/hip_runtime.h>
#include <math.h>

#define NB   8
#define SEQ  2048
#define EMB  8
#define NH   4
#define NFF  2048
#define NTOK (NB*SEQ)          // 16384
#define LNEPS 1e-5f

__device__ __forceinline__ float dot8(const float4& a, const float4& b,
                                      const float4& c, const float4& d) {
    return a.x*b.x + a.y*b.y + a.z*b.z + a.w*b.w
         + c.x*d.x + c.y*d.y + c.z*d.z + c.w*d.w;
}

// ---------------------------------------------------------------------------
// projH[(b*4+h)][s][2] = (x @ Wp^T) head-major, and W2T[f][e] = W2[e][f]
// ---------------------------------------------------------------------------
__global__ __launch_bounds__(128) void k_prep(const float* __restrict__ x,
                                              const float* __restrict__ Wp,
                                              const float* __restrict__ W2,
                                              float* __restrict__ projH,
                                              float* __restrict__ w2t) {
    int t = blockIdx.x * 128 + threadIdx.x;
    if (t < NTOK) {
        int b = t >> 11, s = t & (SEQ - 1);
        const float4* xr = (const float4*)(x + (size_t)t * EMB);
        float4 xa = xr[0], xb = xr[1];
        float o[8];
#pragma unroll
        for (int e = 0; e < 8; ++e) {
            const float4* wr = (const float4*)(Wp + e * EMB);
            o[e] = dot8(xa, wr[0], xb, wr[1]);
        }
#pragma unroll
        for (int h = 0; h < 4; ++h) {
            *(float2*)(projH + ((size_t)(b * 4 + h) * SEQ + s) * 2) =
                make_float2(o[2 * h], o[2 * h + 1]);
        }
    }
    if (t < NFF) {
        float o[8];
#pragma unroll
        for (int e = 0; e < 8; ++e) o[e] = W2[e * NFF + t];
        float4* wr = (float4*)(w2t + (size_t)t * EMB);
        wr[0] = make_float4(o[0], o[1], o[2], o[3]);
        wr[1] = make_float4(o[4], o[5], o[6], o[7]);
    }
}

// ---------------------------------------------------------------------------
// attention v2: 4 queries per thread to cut LDS reads 4x (b128 ~12cyc even
// broadcast -> old kernel was LDS-bound).  QCA=128 queries/block, 8 key-
// subranges (256 keys).  Block 256 thr: qg = tid&31 (32 groups x 4 q),
// sub = tid>>5 (2 distinct LDS addrs per wave instr = free).
// grid = 32 bh x 16 qchunks = 512.  Numerics identical to R5 per (q,k).
// ---------------------------------------------------------------------------
#define QCA 128
__global__ __launch_bounds__(256) void k_attn(const float* __restrict__ projH,
                                              float* __restrict__ ctx) {
    __shared__ float Kx[SEQ];               // 8 KB  (pre-scaled by 1/sqrt2)
    __shared__ float Ky[SEQ];               // 8 KB
    __shared__ float red[3][8][QCA];        // 12 KB

    int bid = blockIdx.x;
    int qc  = bid & 15;                     // 16 query chunks of 128
    int bh  = bid >> 4;                     // (b*4+h)

    const float SC = 0.70710678118654752f;  // 1/sqrt(DK)
    const float4* gsr = (const float4*)(projH + (size_t)bh * SEQ * 2);
#pragma unroll
    for (int ii = 0; ii < 4; ++ii) {
        int i = threadIdx.x + 256 * ii;
        float4 v = gsr[i];                  // keys 2i,2i+1: (x0,y0,x1,y1)
        *(float2*)&Kx[2 * i] = make_float2(v.x * SC, v.z * SC);
        *(float2*)&Ky[2 * i] = make_float2(v.y * SC, v.w * SC);
    }
    __syncthreads();

    int qg  = threadIdx.x & 31;             // 32 query groups of 4
    int sub = threadIdx.x >> 5;             // 8 key subranges

    const float SQ2 = 1.41421356237309505f;
    float qx[4], qy[4], l[4], ax[4], ay[4];
    int q0 = qc * QCA + qg * 4;
#pragma unroll
    for (int u = 0; u < 4; ++u) {
        qx[u] = Kx[q0 + u] * SQ2;           // q back to full scale
        qy[u] = Ky[q0 + u] * SQ2;
        l[u] = 0.f; ax[u] = 0.f; ay[u] = 0.f;
    }

    const float4* Kx4 = (const float4*)Kx;
    const float4* Ky4 = (const float4*)Ky;
    int j04 = sub * 64;                     // 256 keys = 64 float4
#pragma unroll 2
    for (int jj = 0; jj < 64; ++jj) {
        float4 kx = Kx4[j04 + jj];
        float4 ky = Ky4[j04 + jj];
        float kxs[4] = {kx.x, kx.y, kx.z, kx.w};
        float kys[4] = {ky.x, ky.y, ky.z, ky.w};
#pragma unroll
        for (int c = 0; c < 4; ++c) {
#pragma unroll
            for (int u = 0; u < 4; ++u) {
                float s = fmaf(qy[u], kys[c], qx[u] * kxs[c]);
                float p = __expf(s);
                l[u] += p;
                ax[u] = fmaf(p, kxs[c], ax[u]);
                ay[u] = fmaf(p, kys[c], ay[u]);
            }
        }
    }
#pragma unroll
    for (int u = 0; u < 4; ++u) {
        red[0][sub][qg * 4 + u] = l[u];
        red[1][sub][qg * 4 + u] = ax[u];
        red[2][sub][qg * 4 + u] = ay[u];
    }
    __syncthreads();

    if (threadIdx.x < QCA) {
        float L = 0.f, A0 = 0.f, A1 = 0.f;
#pragma unroll
        for (int s = 0; s < 8; ++s) {
            L  += red[0][s][threadIdx.x];
            A0 += red[1][s][threadIdx.x];
            A1 += red[2][s][threadIdx.x];
        }
        float inv = SQ2 / L;                // undo the 1/sqrt2 on staged k
        int b = bh >> 2, h = bh & 3;
        int qglob = qc * QCA + threadIdx.x;
        *(float2*)(ctx + ((size_t)b * SEQ + qglob) * EMB + 2 * h) =
            make_float2(A0 * inv, A1 * inv);
    }
}

// ---------------------------------------------------------------------------
// FUSED post+FFN v3.  512 threads, TB=32 tokens/block, grid=512
// (2 blocks/CU x 8 waves = 4 waves/SIMD).  R2-PROVEN W access: tg = tid&7
// (4 tokens each), sub = tid>>3 (8 distinct W rows per wave instr,
// 8-lane broadcast).  NSUB=64, FCH=32.  Sub-reduce: in-wave shfl_xor
// (8 subs/wave) then 8-wave LDS reduce.  LN2 via 8-lane shuffles.
// ---------------------------------------------------------------------------
#define TB3  32                 // tokens per block
#define FCH3 32                 // f rows per thread (2048 / 64 subs)
__global__ __launch_bounds__(512) void k_ffn3(const float* __restrict__ ctx,
                                              const float* __restrict__ x,
                                              const float* __restrict__ Wo,
                                              const float* __restrict__ g1,
                                              const float* __restrict__ b1,
                                              const float* __restrict__ W1,
                                              const float* __restrict__ bb1,
                                              const float* __restrict__ w2t,
                                              const float* __restrict__ bb2,
                                              const float* __restrict__ g2,
                                              const float* __restrict__ b2,
                                              float* __restrict__ out) {
    __shared__ float q_lds[TB3][8];         // 1 KB
    __shared__ float x1_lds[TB3][8];        // 1 KB
    __shared__ float red[8][TB3][8];        // 8 KB: per-wave partials

    int tid = threadIdx.x;

    // ---- prologue: post-attention for this block's 32 tokens (256 lanes) ----
    if (tid < TB3 * 8) {
        int tl = tid >> 3, e = tid & 7;
        int tok = blockIdx.x * TB3 + tl;
        const float4* cr = (const float4*)(ctx + (size_t)tok * EMB);
        float4 ca = cr[0], cb = cr[1];      // broadcast across the 8 lanes
        const float4* wr = (const float4*)(Wo + e * EMB);
        float ao = dot8(ca, wr[0], cb, wr[1]);
        float y = x[(size_t)tok * EMB + e] + ao;

        float s8 = y;
        s8 += __shfl_xor(s8, 1);
        s8 += __shfl_xor(s8, 2);
        s8 += __shfl_xor(s8, 4);
        float mu = s8 * 0.125f;
        float d  = y - mu;
        float vs = d * d;
        vs += __shfl_xor(vs, 1);
        vs += __shfl_xor(vs, 2);
        vs += __shfl_xor(vs, 4);
        float r = rsqrtf(vs * 0.125f + LNEPS);
        float v = d * r * g1[e] + b1[e];
        x1_lds[tl][e] = v;

        // inclusive prefix product of cos over the 8 lanes of this token
        float p = __cosf(v);
        float t1 = __shfl_up(p, 1, 8); p = (e >= 1) ? p * t1 : p;
        float t2 = __shfl_up(p, 2, 8); p = (e >= 2) ? p * t2 : p;
        float t4 = __shfl_up(p, 4, 8); p = (e >= 4) ? p * t4 : p;
        q_lds[tl][e] = p;
    }
    __syncthreads();

    // ---- main FFN loop: 4 tokens x 32 f rows per thread ----
    int tg  = tid & 7;                      // 8 token groups x 4 tokens
    int sub = tid >> 3;                     // 64 f-subranges
    int tl0 = tg * 4;

    float4 qa[4], qb[4];
#pragma unroll
    for (int k = 0; k < 4; ++k) {
        qa[k] = *(const float4*)&q_lds[tl0 + k][0];   // 8-lane broadcast
        qb[k] = *(const float4*)&q_lds[tl0 + k][4];
    }

    float acc[4][8];
#pragma unroll
    for (int k = 0; k < 4; ++k)
#pragma unroll
        for (int e = 0; e < 8; ++e) acc[k][e] = 0.f;

    int f0 = sub * FCH3;
#pragma unroll 2
    for (int i = 0; i < FCH3; ++i) {
        int f = f0 + i;
        const float4* w1r = (const float4*)(W1 + (size_t)f * EMB);
        float4 wa = w1r[0], wb = w1r[1];
        float bias = bb1[f];
        const float4* w2r = (const float4*)(w2t + (size_t)f * EMB);
        float4 va = w2r[0], vb = w2r[1];
#pragma unroll
        for (int k = 0; k < 4; ++k) {
            float hv = fmaxf(dot8(qa[k], wa, qb[k], wb) + bias, 0.f);
            acc[k][0] = fmaf(hv, va.x, acc[k][0]);
            acc[k][1] = fmaf(hv, va.y, acc[k][1]);
            acc[k][2] = fmaf(hv, va.z, acc[k][2]);
            acc[k][3] = fmaf(hv, va.w, acc[k][3]);
            acc[k][4] = fmaf(hv, vb.x, acc[k][4]);
            acc[k][5] = fmaf(hv, vb.y, acc[k][5]);
            acc[k][6] = fmaf(hv, vb.z, acc[k][6]);
            acc[k][7] = fmaf(hv, vb.w, acc[k][7]);
        }
    }

    // in-wave reduce across the 8 subs resident in this wave (lane bits 3..5)
#pragma unroll
    for (int k = 0; k < 4; ++k)
#pragma unroll
        for (int e = 0; e < 8; ++e) {
            float v = acc[k][e];
            v += __shfl_xor(v, 8);
            v += __shfl_xor(v, 16);
            v += __shfl_xor(v, 32);
            acc[k][e] = v;
        }
    int wv = tid >> 6;                      // 8 waves
    if (((tid >> 3) & 7) == 0) {            // one sub-group per wave writes
#pragma unroll
        for (int k = 0; k < 4; ++k) {
            float4* d0 = (float4*)&red[wv][tl0 + k][0];
            d0[0] = make_float4(acc[k][0], acc[k][1], acc[k][2], acc[k][3]);
            d0[1] = make_float4(acc[k][4], acc[k][5], acc[k][6], acc[k][7]);
        }
    }
    __syncthreads();

    // ---- cross-wave reduce + LN2 (256 lanes = 32 tok x 8 e) ----
    if (tid < TB3 * 8) {
        int rtok = tid >> 3, re = tid & 7;
        float v = 0.f;
#pragma unroll
        for (int w = 0; w < 8; ++w) v += red[w][rtok][re];
        int tok = blockIdx.x * TB3 + rtok;
        v += bb2[re] + x1_lds[rtok][re];

        float s8 = v;
        s8 += __shfl_xor(s8, 1);
        s8 += __shfl_xor(s8, 2);
        s8 += __shfl_xor(s8, 4);
        float mu = s8 * 0.125f;
        float d  = v - mu;
        float vs = d * d;
        vs += __shfl_xor(vs, 1);
        vs += __shfl_xor(vs, 2);
        vs += __shfl_xor(vs, 4);
        float r = rsqrtf(vs * 0.125f + LNEPS);
        out[(size_t)tok * EMB + re] = d * r * g2[re] + b2[re];
    }
}

// ---------------------------------------------------------------------------
extern "C" void kernel_launch(void* const* d_in, const int* in_sizes, int n_in,
                              void* d_out, int out_size, void* d_ws, size_t ws_size,
                              hipStream_t stream) {
    const float* x   = (const float*)d_in[0];
    const float* Wp  = (const float*)d_in[1];
    const float* Wo  = (const float*)d_in[2];
    const float* g1  = (const float*)d_in[3];
    const float* b1  = (const float*)d_in[4];
    const float* W1  = (const float*)d_in[5];
    const float* bb1 = (const float*)d_in[6];
    const float* W2  = (const float*)d_in[7];
    const float* bb2 = (const float*)d_in[8];
    const float* g2  = (const float*)d_in[9];
    const float* b2  = (const float*)d_in[10];
    float* out = (float*)d_out;

    float* ws    = (float*)d_ws;
    float* projH = ws;                // 131072 f32 (head-major)
    float* ctx   = ws + 131072;       // 131072 f32
    float* w2t   = ws + 262144;       // 16384 f32

    hipLaunchKernelGGL(k_prep, dim3(NTOK / 128), dim3(128), 0, stream,
                       x, Wp, W2, projH, w2t);
    hipLaunchKernelGGL(k_attn, dim3((NB * NH) * (SEQ / QCA)), dim3(256), 0, stream,
                       projH, ctx);
    hipLaunchKernelGGL(k_ffn3, dim3(NTOK / TB3), dim3(512), 0, stream,
                       ctx, x, Wo, g1, b1, W1, bb1, w2t, bb2, g2, b2, out);
}